// Round 1
// baseline (1647.552 us; speedup 1.0000x reference)
//
#include <hip/hip_runtime.h>
#include <stdint.h>
#include <stddef.h>

// SoftTree: x(16384,512) f32; gw(512,255); gb(255); pw(256,512,64); pb(256,1,64)
// out0 (256,16384,64) = act(einsum(bi,lio->lbo) + pb); out1 (256,16384) leaf probs.
#define BATCH   16384
#define INFEAT  512
#define OUTF    64
#define LEAVES  256
#define NTOT    16384          // LEAVES*OUTF
#define PI_F    3.14159265358979323846f

typedef _Float16 v8h __attribute__((ext_vector_type(8)));
typedef float    v4f __attribute__((ext_vector_type(4)));

// ws layout (bytes)
#define WS_X16  0                          // 16384*512*2   = 16 MiB  (x fp16)
#define WS_PWT  16777216                   // 16384*512*2   = 16 MiB  (pw^T fp16: [l][o][k])
#define WS_GWT  (2*16777216)               // 256*512*2     = 256 KiB (gw^T fp16, row 255 = 0)
#define WS_LOG  (2*16777216 + 262144)      // 16384*256*4   = 16 MiB  (gate logits f32)
#define WS_NEED (WS_LOG + 16777216)

#define GLOAD_LDS16(g, l)                                              \
  __builtin_amdgcn_global_load_lds(                                    \
      (const __attribute__((address_space(1))) void*)(g),              \
      (__attribute__((address_space(3))) void*)(l), 16, 0, 0)

// ---- x fp32 -> fp16, 8 elems/thread ----------------------------------------
__global__ __launch_bounds__(256) void k_convert_x(const float* __restrict__ x,
                                                   _Float16* __restrict__ x16) {
  int i = blockIdx.x * 256 + threadIdx.x;        // 1,048,576 threads
  const float4* src = (const float4*)x + (size_t)i * 2;
  float4 a = src[0], b = src[1];
  v8h h;
  h[0] = (_Float16)a.x; h[1] = (_Float16)a.y; h[2] = (_Float16)a.z; h[3] = (_Float16)a.w;
  h[4] = (_Float16)b.x; h[5] = (_Float16)b.y; h[6] = (_Float16)b.z; h[7] = (_Float16)b.w;
  *((v8h*)x16 + i) = h;
}

// ---- pw (l,k,o) f32 -> pwt (l,o,k) fp16, 64x64 LDS tile transpose ----------
__global__ __launch_bounds__(256) void k_transpose_pw(const float* __restrict__ pw,
                                                      _Float16* __restrict__ pwt) {
  __shared__ float tile[64][65];
  int l = blockIdx.x >> 3, kt = blockIdx.x & 7;
  int k0 = kt * 64, t = threadIdx.x;
  for (int i = t; i < 4096; i += 256) {
    int kl = i >> 6, o = i & 63;
    tile[kl][o] = pw[(size_t)l * 32768 + (size_t)(k0 + kl) * 64 + o];
  }
  __syncthreads();
  for (int i = t; i < 4096; i += 256) {
    int o = i >> 6, kl = i & 63;
    pwt[((size_t)l * 64 + o) * 512 + k0 + kl] = (_Float16)tile[kl][o];
  }
}

// ---- gw (k,255) f32 -> gwt (256,k) fp16, row 255 zero ----------------------
__global__ __launch_bounds__(256) void k_transpose_gw(const float* __restrict__ gw,
                                                      _Float16* __restrict__ gwt) {
  __shared__ float tile[64][65];
  int kt = blockIdx.x >> 2, nt = blockIdx.x & 3;
  int k0 = kt * 64, n0 = nt * 64, t = threadIdx.x;
  for (int i = t; i < 4096; i += 256) {
    int kl = i >> 6, o = i & 63;
    int og = n0 + o;
    tile[kl][o] = (og < 255) ? gw[(size_t)(k0 + kl) * 255 + og] : 0.f;
  }
  __syncthreads();
  for (int i = t; i < 4096; i += 256) {
    int o = i >> 6, kl = i & 63;
    gwt[(size_t)(n0 + o) * 512 + k0 + kl] = (_Float16)tile[kl][o];
  }
}

// ---- GEMM: C(MxN) = A(Mx512) * Bt(Nx512)^T, fp16 MFMA, f32 acc -------------
// MODE 0: main einsum -> activation epilogue into d_out (bias = pb[16384])
// MODE 1: gate logits -> ws (bias = gb[255])
// Block 128x128, BK=64, 4 waves of 64x64. LDS in fragment order with slot
// swizzle slot(m15,q,s) = (q<<4) | ((m15+q+4s)&15)  -> conflict-free b128 reads.
template <int MODE>
__global__ __launch_bounds__(256) void k_gemm(const _Float16* __restrict__ A,
                                              const _Float16* __restrict__ Bt,
                                              float* __restrict__ out,
                                              const float* __restrict__ bias) {
  __shared__ __align__(16) _Float16 lds[16384];  // A halves [0,8192), B [8192,16384)
  const int t = threadIdx.x;
  const int lane = t & 63, w = t >> 6;
  const int q = lane >> 4, l15 = lane & 15;

  int mt, nt;
  if (MODE == 0) {
    // XCD-pinned 16x16-tile supertiles: xcd = pid&7 owns supertile column xcd.
    int pid = blockIdx.x;
    int xcd = pid & 7, seq = pid >> 3;
    int stl = seq >> 8, idx = seq & 255;
    mt = stl * 16 + (idx >> 4);
    nt = xcd * 16 + (idx & 15);
  } else {
    mt = blockIdx.x >> 1;
    nt = blockIdx.x & 1;
  }
  const int m0 = mt * 128, n0 = nt * 128;

  // staging: region r = w*4+i covers (s=r>>3, mb=r&7); lane L lands at slot L.
  // inverse: m15 = (L&15) - (L>>4) - 4s (mod 16); row = mb*16+m15; col = s*32+(L>>4)*8
  const _Float16* gA[4];
  const _Float16* gB[4];
  int ldsA_off[4], ldsB_off[4];
#pragma unroll
  for (int i = 0; i < 4; ++i) {
    int r = w * 4 + i;
    int s = r >> 3, mb = r & 7;
    int m15 = (l15 - q - 4 * s) & 15;
    int row = mb * 16 + m15;
    int col = s * 32 + q * 8;
    gA[i] = A + (size_t)(m0 + row) * 512 + col;
    gB[i] = Bt + (size_t)(n0 + row) * 512 + col;
    ldsA_off[i] = r * 512;          // halves
    ldsB_off[i] = 8192 + r * 512;
  }
  const int slot0 = (q << 4) | ((l15 + q) & 15);
  const int slot1 = (q << 4) | ((l15 + q + 4) & 15);
  const int wm4 = (w >> 1) * 4, wn4 = (w & 1) * 4;

  v4f acc[4][4];
#pragma unroll
  for (int mb = 0; mb < 4; ++mb)
#pragma unroll
    for (int nb = 0; nb < 4; ++nb) {
      v4f z = {0.f, 0.f, 0.f, 0.f};
      acc[mb][nb] = z;
    }

  for (int kt2 = 0; kt2 < 8; ++kt2) {
    __syncthreads();
#pragma unroll
    for (int i = 0; i < 4; ++i) {
      GLOAD_LDS16(gA[i], &lds[ldsA_off[i]]);
      gA[i] += 64;
    }
#pragma unroll
    for (int i = 0; i < 4; ++i) {
      GLOAD_LDS16(gB[i], &lds[ldsB_off[i]]);
      gB[i] += 64;
    }
    __syncthreads();  // compiler emits s_waitcnt vmcnt(0) before s_barrier
#pragma unroll
    for (int s = 0; s < 2; ++s) {
      const int slot = s ? slot1 : slot0;
      v8h a[4], b[4];
#pragma unroll
      for (int mb = 0; mb < 4; ++mb)
        a[mb] = *(const v8h*)&lds[((s * 8 + wm4 + mb) * 64 + slot) * 8];
#pragma unroll
      for (int nb = 0; nb < 4; ++nb)
        b[nb] = *(const v8h*)&lds[8192 + ((s * 8 + wn4 + nb) * 64 + slot) * 8];
#pragma unroll
      for (int mb = 0; mb < 4; ++mb)
#pragma unroll
        for (int nb = 0; nb < 4; ++nb)
          acc[mb][nb] =
              __builtin_amdgcn_mfma_f32_16x16x32_f16(a[mb], b[nb], acc[mb][nb], 0, 0, 0);
    }
  }

  // epilogue: D[m][n], m = q*4 + reg, n = l15 within each 16x16 tile
  const int wm = (w >> 1) * 64, wn = (w & 1) * 64;
#pragma unroll
  for (int mb = 0; mb < 4; ++mb) {
#pragma unroll
    for (int nb = 0; nb < 4; ++nb) {
      int m = m0 + wm + mb * 16 + q * 4;
      int n = n0 + wn + nb * 16 + l15;
#pragma unroll
      for (int r = 0; r < 4; ++r) {
        float v = acc[mb][nb][r];
        if (MODE == 0) {
          v += bias[n];  // pb flat is exactly [n]
          float res;
          if ((n & 63) < 32) {  // uniform per nb (tile-of-16 aligned)
            float e = __expf(2.f * v);
            res = PI_F * (1.f - 2.f * __builtin_amdgcn_rcpf(1.f + e));
          } else {
            res = __builtin_amdgcn_rcpf(1.f + __expf(-v));
          }
          out[(size_t)(n >> 6) * 1048576 + (size_t)(m + r) * 64 + (n & 63)] = res;
        } else {
          float bv = (n < 255) ? bias[n] : 0.f;
          out[(size_t)(m + r) * 256 + n] = v + bv;
        }
      }
    }
  }
}

// ---- leaf probabilities from gate logits -----------------------------------
// block: 32 batch rows x all 256 leaves; g_sh[gate][b] stride 33 (conflict-free)
__global__ __launch_bounds__(256) void k_leaf(const float* __restrict__ logits,
                                              float* __restrict__ out1) {
  __shared__ float g_sh[255 * 33];
  const int t = threadIdx.x;
  const int b0 = blockIdx.x * 32;
  for (int i = t; i < 32 * 256; i += 256) {
    int b = i >> 8, gate = i & 255;
    float v = logits[(size_t)(b0 + b) * 256 + gate];
    float s = __builtin_amdgcn_rcpf(1.f + __expf(-v));
    if (gate < 255) g_sh[gate * 33 + b] = s;
  }
  __syncthreads();
  const int b = t & 31;
  const int lbase = t >> 5;  // 0..7
  for (int j = 0; j < 32; ++j) {
    int l = lbase + j * 8;
    float p = 1.f;
    int node = 0;
#pragma unroll
    for (int d = 0; d < 8; ++d) {
      int gate = (1 << d) - 1 + node;
      int bit = (l >> (7 - d)) & 1;
      float gv = g_sh[gate * 33 + b];
      p *= bit ? (1.f - gv) : gv;
      node = 2 * node + bit;
    }
    out1[(size_t)l * 16384 + b0 + b] = p;
  }
}

extern "C" void kernel_launch(void* const* d_in, const int* in_sizes, int n_in,
                              void* d_out, int out_size, void* d_ws, size_t ws_size,
                              hipStream_t stream) {
  const float* x  = (const float*)d_in[0];
  const float* gw = (const float*)d_in[1];
  const float* gb = (const float*)d_in[2];
  const float* pw = (const float*)d_in[3];
  const float* pb = (const float*)d_in[4];

  if (ws_size < (size_t)WS_NEED) return;  // clean fail -> diagnoses small ws

  char* ws = (char*)d_ws;
  _Float16* x16    = (_Float16*)(ws + WS_X16);
  _Float16* pwt    = (_Float16*)(ws + WS_PWT);
  _Float16* gwt    = (_Float16*)(ws + WS_GWT);
  float*    logits = (float*)(ws + WS_LOG);
  float* out0 = (float*)d_out;
  float* out1 = out0 + (size_t)LEAVES * BATCH * OUTF;

  hipLaunchKernelGGL(k_convert_x,    dim3(4096), dim3(256), 0, stream, x, x16);
  hipLaunchKernelGGL(k_transpose_pw, dim3(2048), dim3(256), 0, stream, pw, pwt);
  hipLaunchKernelGGL(k_transpose_gw, dim3(32),   dim3(256), 0, stream, gw, gwt);
  hipLaunchKernelGGL((k_gemm<1>),    dim3(256),  dim3(256), 0, stream, x16, gwt, logits, gb);
  hipLaunchKernelGGL(k_leaf,         dim3(512),  dim3(256), 0, stream, logits, out1);
  hipLaunchKernelGGL((k_gemm<0>),    dim3(16384),dim3(256), 0, stream, x16, pwt, out0, pb);
}